// Round 2
// baseline (1500.102 us; speedup 1.0000x reference)
//
#include <hip/hip_runtime.h>
#include <hip/hip_bf16.h>
#include <stdint.h>

typedef short bf16x8 __attribute__((ext_vector_type(8)));
typedef float f32x4 __attribute__((ext_vector_type(4)));
typedef unsigned short u16;
typedef unsigned int u32;

#define B_TOT 8192
#define NN 25

__device__ __forceinline__ u16 f2bf(float f) {
  u32 u = __float_as_uint(f);
  u32 r = (u + 0x7fffu + ((u >> 16) & 1u)) >> 16;   // RNE
  return (u16)r;
}
__device__ __forceinline__ float bf2f(u16 h) {
  return __uint_as_float(((u32)h) << 16);
}

// ---- group tables -------------------------------------------------------
__device__ __constant__ int d_IDXT[5][25] = {
  {0,1,2,3,4,5,6,7,8,9,10,11,12,13,14,15,16,17,18,19,20,21,22,23,24},
  {0,1,2,3,4,5,6,7,8, 0,0,0,0,0,0,0,0,0,0,0,0,0,0,0,0},
  {0,9,10,11,12,13,14, 0,0,0,0,0,0,0,0,0,0,0,0,0,0,0,0,0,0},
  {6,7,8,12,13,14, 0,0,0,0,0,0,0,0,0,0,0,0,0,0,0,0,0,0,0},
  {3,4,5,9,10,11, 0,0,0,0,0,0,0,0,0,0,0,0,0,0,0,0,0,0,0}
};
__device__ __constant__ int d_NG[5]    = {25, 9, 7, 6, 6};
__device__ __constant__ int d_BW[5]    = {1, 3, 4, 5, 5};       // batches per 32-row window
__device__ __constant__ int d_PREFN[5] = {0, 25, 34, 41, 47};   // prefix of n_g
// gather contributor tables: per output node v, list of (group, pos-in-group)
__device__ __constant__ int d_GCNT[25] = {3,2,2,3,3,3,3,3,3,3,3,3,3,3,3,1,1,1,1,1,1,1,1,1,1};
__device__ __constant__ signed char d_GG[25][3] = {
  {0,1,2},{0,1,0},{0,1,0},{0,1,4},{0,1,4},{0,1,4},{0,1,3},{0,1,3},{0,1,3},
  {0,2,4},{0,2,4},{0,2,4},{0,2,3},{0,2,3},{0,2,3},
  {0,0,0},{0,0,0},{0,0,0},{0,0,0},{0,0,0},{0,0,0},{0,0,0},{0,0,0},{0,0,0},{0,0,0}};
__device__ __constant__ signed char d_GP[25][3] = {
  {0,0,0},{1,1,0},{2,2,0},{3,3,0},{4,4,1},{5,5,2},{6,6,0},{7,7,1},{8,8,2},
  {9,1,3},{10,2,4},{11,3,5},{12,4,3},{13,5,4},{14,6,5},
  {15,0,0},{16,0,0},{17,0,0},{18,0,0},{19,0,0},{20,0,0},{21,0,0},{22,0,0},{23,0,0},{24,0,0}};

// ---- prep: W1 [5][256][512] -> w1t bf16 [5][512][256];  W2 [5][512][256] -> w2t bf16 [5][256][512]
__global__ __launch_bounds__(256) void prep_kernel(const float* __restrict__ W1,
                                                   const float* __restrict__ W2,
                                                   u16* __restrict__ w1t,
                                                   u16* __restrict__ w2t) {
  __shared__ float tile[32][33];
  int bid = blockIdx.x, t = threadIdx.x;
  const float* src; u16* dst; int R, C, tr, tc;
  if (bid < 640) {
    int g = bid >> 7, tI = bid & 127;
    R = 256; C = 512; tr = tI >> 4; tc = tI & 15;
    src = W1 + (size_t)g * 131072; dst = w1t + (size_t)g * 131072;
  } else {
    int b2 = bid - 640; int g = b2 >> 7, tI = b2 & 127;
    R = 512; C = 256; tr = tI >> 3; tc = tI & 7;
    src = W2 + (size_t)g * 131072; dst = w2t + (size_t)g * 131072;
  }
  for (int e = t; e < 1024; e += 256) {
    int r = e >> 5, c = e & 31;
    tile[r][c] = src[(size_t)(tr * 32 + r) * C + tc * 32 + c];
  }
  __syncthreads();
  for (int e = t; e < 1024; e += 256) {
    int c = e >> 5, r = e & 31;
    dst[(size_t)(tc * 32 + c) * R + tr * 32 + r] = f2bf(tile[r][c]);
  }
}

// ---- main per-group fused kernel ---------------------------------------
// grid: 4063 blocks; block b -> (group, tile). M = 128 rows (4 windows of 32),
// each window packs bw batches of n_g rows. 512 threads = 8 waves (2x4 wave grid).
struct __align__(16) SMem {
  u16 xs[120 * 256];   // staged x (bf16, swizzled), rows = b_local*ng + i
  u16 wt[128 * 64];    // weight tile [ncol][k] (swizzled)
  u16 bd[128 * 32];    // block-diag norm_adj (swizzled, (row&3)<<4)
  u16 u[256 * 128];    // chunk: sT=[0:128)x128 (S^T), hs=+32KB [128]x[128]; final: s2T [256][128]
  float b1s[512];
  float b2s[256];
  float dinv[500];     // [b_local*25 + i]
  u16 rowLUT[128];     // valid<<15 | b_local<<5 | i
};
static_assert(sizeof(SMem) <= 160 * 1024, "LDS overflow");

__global__ __launch_bounds__(512) void gcn_group_kernel(
    const float* __restrict__ x, const float* __restrict__ adj,
    const float* __restrict__ b1, const float* __restrict__ b2,
    const float* __restrict__ fw,
    const u16* __restrict__ w1t, const u16* __restrict__ w2t,
    u16* __restrict__ wsout, float* __restrict__ out, int use_ws) {
  __shared__ SMem sm;
  int bid = blockIdx.x;
  int g, tile;
  if (bid < 2048)      { g = 0; tile = bid; }
  else if (bid < 2731) { g = 1; tile = bid - 2048; }
  else if (bid < 3243) { g = 2; tile = bid - 2731; }
  else if (bid < 3653) { g = 3; tile = bid - 3243; }
  else                 { g = 4; tile = bid - 3653; }
  const int ng = d_NG[g], bw = d_BW[g];
  const int tb = bw * 4;               // batches per block
  const int tb0 = tile * tb;
  const int tid = threadIdx.x;
  const int lane = tid & 63, wid = tid >> 6, wm = wid >> 2, wn = wid & 3;

  // rowLUT: Mrow -> (valid, b_local, i)
  if (tid < 128) {
    int w = tid >> 5, off = tid & 31;
    int j = off / ng, i = off - j * ng;
    int valid = (j < bw) ? 1 : 0;
    int bl = w * bw + j;
    sm.rowLUT[tid] = (u16)((valid << 15) | ((bl & 31) << 5) | i);
  }
  sm.b1s[tid] = b1[g * 512 + tid];
  if (tid < 256) sm.b2s[tid] = b2[g * 256 + tid];

  // stage x -> bf16 LDS (swizzled); zero-fill batches >= B_TOT
  const int nrows = tb * ng;
  for (int cid = tid; cid < nrows * 64; cid += 512) {
    int r = cid >> 6, c4 = cid & 63;
    int bl = r / ng, i = r - bl * ng;
    int b = tb0 + bl;
    float4 v = make_float4(0.f, 0.f, 0.f, 0.f);
    if (b < B_TOT) {
      const float* p = x + ((size_t)b * NN + d_IDXT[g][i]) * 256 + c4 * 4;
      v = *(const float4*)p;
    }
    u32 p0 = (u32)f2bf(v.x) | ((u32)f2bf(v.y) << 16);
    u32 p1 = (u32)f2bf(v.z) | ((u32)f2bf(v.w) << 16);
    u32 off = (u32)r * 512u + (((u32)c4 * 8u) ^ (((u32)r & 7u) << 4));
    *(uint2*)((char*)sm.xs + off) = make_uint2(p0, p1);
  }

  // degrees -> dinv
  if (tid < nrows) {
    int bl = tid / ng, i = tid - bl * ng;
    int b = tb0 + bl;
    float s = 1.0f;  // +I diagonal
    if (b < B_TOT) {
      const float* ar = adj + ((size_t)b * NN + d_IDXT[g][i]) * NN;
      for (int j2 = 0; j2 < ng; ++j2) s += ar[d_IDXT[g][j2]];
    }
    sm.dinv[bl * 25 + i] = (s > 0.f) ? rsqrtf(s) : 0.f;
  }
  __syncthreads();

  // per-lane A-row bases (xs row per Mfrag), invalid rows clamped to row 0
  u32 arow[4], aswz[4];
#pragma unroll
  for (int m = 0; m < 4; ++m) {
    int r = wm * 64 + m * 16 + (lane & 15);
    u16 lut = sm.rowLUT[r];
    int rxs = 0;
    if (lut & 0x8000) rxs = ((lut >> 5) & 31) * ng + (lut & 31);
    arow[m] = (u32)rxs * 512u;
    aswz[m] = ((u32)rxs & 7u) << 4;
  }

  // build BD (block-diagonal normalized adjacency), bf16, swizzled (row&3)<<4
  for (int e = tid; e < 4096; e += 512) {
    int r = e >> 5, c = e & 31;
    u16 lr = sm.rowLUT[r];
    u16 lc = sm.rowLUT[(r & ~31) | c];
    float val = 0.f;
    int blr = (lr >> 5) & 31, ir = lr & 31;
    int blc = (lc >> 5) & 31, ic = lc & 31;
    int b = tb0 + blr;
    if ((lr >> 15) && (lc >> 15) && blr == blc && b < B_TOT) {
      float a = adj[((size_t)b * NN + d_IDXT[g][ir]) * NN + d_IDXT[g][ic]] +
                (ir == ic ? 1.f : 0.f);
      val = sm.dinv[blr * 25 + ir] * a * sm.dinv[blr * 25 + ic];
    }
    u32 off = (u32)r * 64u + (((u32)c * 2u) ^ (((u32)r & 3u) << 4));
    *(u16*)((char*)sm.bd + off) = f2bf(val);
  }

  float wg = 0.2f;
  if (!use_ws) {  // softmax weight needed only for atomic path
    float a0 = fw[0], a1 = fw[1], a2 = fw[2], a3 = fw[3], a4 = fw[4];
    float mx = fmaxf(fmaxf(fmaxf(a0, a1), fmaxf(a2, a3)), a4);
    float e0 = __expf(a0 - mx), e1 = __expf(a1 - mx), e2 = __expf(a2 - mx),
          e3 = __expf(a3 - mx), e4 = __expf(a4 - mx);
    float es[5] = {e0, e1, e2, e3, e4};
    wg = es[g] / (e0 + e1 + e2 + e3 + e4);
  }

  f32x4 zero4 = {0.f, 0.f, 0.f, 0.f};
  f32x4 accO[4][2][2];
#pragma unroll
  for (int m = 0; m < 4; ++m)
#pragma unroll
    for (int a = 0; a < 2; ++a)
#pragma unroll
      for (int bq = 0; bq < 2; ++bq) accO[m][a][bq] = zero4;

  // ---- 4 chunks of 128 hidden features ----
#pragma unroll 1
  for (int c = 0; c < 4; ++c) {
    f32x4 accS[4][2];
#pragma unroll
    for (int m = 0; m < 4; ++m) { accS[m][0] = zero4; accS[m][1] = zero4; }

    // GEMM1: S_c = X (M x 256) @ W1[:, c*128 : +128]
    for (int kt = 0; kt < 4; ++kt) {
#pragma unroll
      for (int it = 0; it < 2; ++it) {
        int cid = tid + it * 512;
        int row = cid >> 3, p = cid & 7;
        const u16* src = w1t + (size_t)(g * 512 + c * 128 + row) * 256 + kt * 64 + p * 8;
        uint4 v = *(const uint4*)src;
        u32 off = (u32)row * 128u + (((u32)p * 16u) ^ (((u32)row & 7u) << 4));
        *(uint4*)((char*)sm.wt + off) = v;
      }
      __syncthreads();
#pragma unroll
      for (int ks = 0; ks < 2; ++ks) {
        u32 colb = (u32)(kt * 128 + ks * 64) + (((u32)lane >> 4) << 4);
        bf16x8 afr[4];
#pragma unroll
        for (int m = 0; m < 4; ++m)
          afr[m] = *(const bf16x8*)((const char*)sm.xs + arow[m] + (colb ^ aswz[m]));
#pragma unroll
        for (int nf = 0; nf < 2; ++nf) {
          int nl = (wn * 2 + nf) * 16 + (lane & 15);
          u32 boff = (u32)nl * 128u +
                     (((u32)(ks * 64) + (((u32)lane >> 4) << 4)) ^ (((u32)nl & 7u) << 4));
          bf16x8 bfr = *(const bf16x8*)((const char*)sm.wt + boff);
#pragma unroll
          for (int m = 0; m < 4; ++m)
            accS[m][nf] = __builtin_amdgcn_mfma_f32_16x16x32_bf16(afr[m], bfr, accS[m][nf], 0, 0, 0);
        }
      }
      __syncthreads();
    }

    // write S^T (bf16, swizzled): sT[f][Mrow], f in [0,128)
#pragma unroll
    for (int m = 0; m < 4; ++m) {
      int mrow0 = wm * 64 + m * 16 + ((lane >> 4) << 2);
#pragma unroll
      for (int nf = 0; nf < 2; ++nf) {
        int f = (wn * 2 + nf) * 16 + (lane & 15);
        u32 p0 = (u32)f2bf(accS[m][nf][0]) | ((u32)f2bf(accS[m][nf][1]) << 16);
        u32 p1 = (u32)f2bf(accS[m][nf][2]) | ((u32)f2bf(accS[m][nf][3]) << 16);
        u32 off = (u32)f * 256u + (((u32)mrow0 * 2u) ^ (((u32)f & 7u) << 4));
        *(uint2*)((char*)sm.u + off) = make_uint2(p0, p1);
      }
    }
    __syncthreads();

    // mix1: H = relu(BD @ S + b1), write hs[Mrow][f]
#pragma unroll
    for (int m = 0; m < 4; ++m) {
      int mf = wm * 4 + m, win = mf >> 1;
      int br = mf * 16 + (lane & 15);
      u32 aoff = (u32)br * 64u + (((((u32)lane >> 4) << 4)) ^ (((u32)br & 3u) << 4));
      bf16x8 abd = *(const bf16x8*)((const char*)sm.bd + aoff);
#pragma unroll
      for (int nf = 0; nf < 2; ++nf) {
        int f = (wn * 2 + nf) * 16 + (lane & 15);
        u32 boff = (u32)f * 256u +
                   (((u32)(win * 64) + (((u32)lane >> 4) << 4)) ^ (((u32)f & 7u) << 4));
        bf16x8 bfr = *(const bf16x8*)((const char*)sm.u + boff);
        f32x4 d = zero4;
        d = __builtin_amdgcn_mfma_f32_16x16x32_bf16(abd, bfr, d, 0, 0, 0);
        float bb = sm.b1s[c * 128 + f];
#pragma unroll
        for (int r2 = 0; r2 < 4; ++r2) {
          int mrow = mf * 16 + ((lane >> 4) << 2) + r2;
          float hv = d[r2] + bb;
          hv = hv > 0.f ? hv : 0.f;
          u32 hoff = 32768u + (u32)mrow * 256u + (((u32)f * 2u) ^ (((u32)mrow & 7u) << 4));
          *(u16*)((char*)sm.u + hoff) = f2bf(hv);
        }
      }
    }
    __syncthreads();

    // GEMM2 partial: accO += H (M x 128) @ W2[c*128 : +128, :]
#pragma unroll
    for (int nh = 0; nh < 2; ++nh) {
#pragma unroll
      for (int kt2 = 0; kt2 < 2; ++kt2) {
#pragma unroll
        for (int it = 0; it < 2; ++it) {
          int cid = tid + it * 512;
          int row = cid >> 3, p = cid & 7;
          const u16* src = w2t + (size_t)(g * 256 + nh * 128 + row) * 512 +
                           c * 128 + kt2 * 64 + p * 8;
          uint4 v = *(const uint4*)src;
          u32 off = (u32)row * 128u + (((u32)p * 16u) ^ (((u32)row & 7u) << 4));
          *(uint4*)((char*)sm.wt + off) = v;
        }
        __syncthreads();
#pragma unroll
        for (int ks = 0; ks < 2; ++ks) {
          bf16x8 afr[4];
#pragma unroll
          for (int m = 0; m < 4; ++m) {
            int mrow = wm * 64 + m * 16 + (lane & 15);
            u32 aoff = 32768u + (u32)mrow * 256u +
                       (((u32)(kt2 * 128 + ks * 64) + (((u32)lane >> 4) << 4)) ^
                        (((u32)mrow & 7u) << 4));
            afr[m] = *(const bf16x8*)((const char*)sm.u + aoff);
          }
#pragma unroll
          for (int nf = 0; nf < 2; ++nf) {
            int nl = (wn * 2 + nf) * 16 + (lane & 15);
            u32 boff = (u32)nl * 128u +
                       (((u32)(ks * 64) + (((u32)lane >> 4) << 4)) ^ (((u32)nl & 7u) << 4));
            bf16x8 bfr = *(const bf16x8*)((const char*)sm.wt + boff);
#pragma unroll
            for (int m = 0; m < 4; ++m)
              accO[m][nh][nf] =
                  __builtin_amdgcn_mfma_f32_16x16x32_bf16(afr[m], bfr, accO[m][nh][nf], 0, 0, 0);
          }
        }
        __syncthreads();
      }
    }
  }  // chunks

  // write S2^T [256][128] (bf16, swizzled) over full u buffer
#pragma unroll
  for (int m = 0; m < 4; ++m) {
    int mrow0 = wm * 64 + m * 16 + ((lane >> 4) << 2);
#pragma unroll
    for (int nh = 0; nh < 2; ++nh)
#pragma unroll
      for (int nf = 0; nf < 2; ++nf) {
        int f = nh * 128 + (wn * 2 + nf) * 16 + (lane & 15);
        u32 p0 = (u32)f2bf(accO[m][nh][nf][0]) | ((u32)f2bf(accO[m][nh][nf][1]) << 16);
        u32 p1 = (u32)f2bf(accO[m][nh][nf][2]) | ((u32)f2bf(accO[m][nh][nf][3]) << 16);
        u32 off = (u32)f * 256u + (((u32)mrow0 * 2u) ^ (((u32)f & 7u) << 4));
        *(uint2*)((char*)sm.u + off) = make_uint2(p0, p1);
      }
  }
  __syncthreads();

  // mix2: out_g = relu(BD @ S2 + b2); emit
  u16* wbase = wsout + (size_t)d_PREFN[g] * B_TOT * 256;
#pragma unroll
  for (int m = 0; m < 4; ++m) {
    int mf = wm * 4 + m, win = mf >> 1;
    int br = mf * 16 + (lane & 15);
    u32 aoff = (u32)br * 64u + (((((u32)lane >> 4) << 4)) ^ (((u32)br & 3u) << 4));
    bf16x8 abd = *(const bf16x8*)((const char*)sm.bd + aoff);
#pragma unroll
    for (int q = 0; q < 4; ++q) {
      int f = (wn * 4 + q) * 16 + (lane & 15);
      u32 boff = (u32)f * 256u +
                 (((u32)(win * 64) + (((u32)lane >> 4) << 4)) ^ (((u32)f & 7u) << 4));
      bf16x8 bfr = *(const bf16x8*)((const char*)sm.u + boff);
      f32x4 d = zero4;
      d = __builtin_amdgcn_mfma_f32_16x16x32_bf16(abd, bfr, d, 0, 0, 0);
      float bb = sm.b2s[f];
#pragma unroll
      for (int r2 = 0; r2 < 4; ++r2) {
        int mrow = mf * 16 + ((lane >> 4) << 2) + r2;
        u16 lut = sm.rowLUT[mrow];
        if (!(lut & 0x8000)) continue;
        int bl = (lut >> 5) & 31, i = lut & 31;
        int b = tb0 + bl;
        if (b >= B_TOT) continue;
        float v = d[r2] + bb;
        v = v > 0.f ? v : 0.f;
        if (use_ws) {
          wbase[((size_t)b * ng + i) * 256 + f] = f2bf(v);
        } else {
          float* dst = out + ((size_t)b * NN + d_IDXT[g][i]) * 256 + f;
          __hip_atomic_fetch_add(dst, wg * v, __ATOMIC_RELAXED, __HIP_MEMORY_SCOPE_AGENT);
        }
      }
    }
  }
}

// ---- gather: out[b][v][f] = sum_g w_g * wsout_g[b][pos][f] --------------
__global__ __launch_bounds__(256) void gather_kernel(const u16* __restrict__ wsout,
                                                     const float* __restrict__ fw,
                                                     float* __restrict__ out) {
  int t = blockIdx.x * 256 + threadIdx.x;   // one quad of floats
  int b = t / 1600;                          // 25*256/4 per batch
  int rem = t - b * 1600;
  int v = rem >> 6;
  int f = (rem & 63) << 2;
  float a0 = fw[0], a1 = fw[1], a2 = fw[2], a3 = fw[3], a4 = fw[4];
  float mx = fmaxf(fmaxf(fmaxf(a0, a1), fmaxf(a2, a3)), a4);
  float e0 = __expf(a0 - mx), e1 = __expf(a1 - mx), e2 = __expf(a2 - mx),
        e3 = __expf(a3 - mx), e4 = __expf(a4 - mx);
  float inv = 1.f / (e0 + e1 + e2 + e3 + e4);
  float w[5] = {e0 * inv, e1 * inv, e2 * inv, e3 * inv, e4 * inv};
  float acc0 = 0.f, acc1 = 0.f, acc2 = 0.f, acc3 = 0.f;
  int cnt = d_GCNT[v];
  for (int k = 0; k < cnt; ++k) {
    int g = d_GG[v][k], pos = d_GP[v][k];
    const u16* p = wsout + (size_t)d_PREFN[g] * B_TOT * 256 +
                   ((size_t)b * d_NG[g] + pos) * 256 + f;
    ushort4 h = *(const ushort4*)p;
    float ww = w[g];
    acc0 += ww * bf2f(h.x);
    acc1 += ww * bf2f(h.y);
    acc2 += ww * bf2f(h.z);
    acc3 += ww * bf2f(h.w);
  }
  *(float4*)(out + (size_t)t * 4) = make_float4(acc0, acc1, acc2, acc3);
}

// ---- host launch --------------------------------------------------------
extern "C" void kernel_launch(void* const* d_in, const int* in_sizes, int n_in,
                              void* d_out, int out_size, void* d_ws, size_t ws_size,
                              hipStream_t stream) {
  const float* x   = (const float*)d_in[0];
  const float* adj = (const float*)d_in[1];
  const float* W1  = (const float*)d_in[2];
  const float* b1  = (const float*)d_in[3];
  const float* W2  = (const float*)d_in[4];
  const float* b2  = (const float*)d_in[5];
  const float* fw  = (const float*)d_in[6];
  float* out = (float*)d_out;
  char* ws = (char*)d_ws;

  u16* w1t   = (u16*)ws;                        // 5*512*256*2 = 1310720 B
  u16* w2t   = (u16*)(ws + 1310720);            // 1310720 B
  u16* wsout = (u16*)(ws + 2621440);            // 53*8192*256*2 = 222298112 B
  const size_t need = 2621440ull + 53ull * 8192ull * 256ull * 2ull;
  const int use_ws = (ws_size >= need) ? 1 : 0;

  prep_kernel<<<1280, 256, 0, stream>>>(W1, W2, w1t, w2t);
  if (!use_ws) {
    hipMemsetAsync(out, 0, (size_t)out_size * sizeof(float), stream);
  }
  gcn_group_kernel<<<4063, 512, 0, stream>>>(x, adj, b1, b2, fw, w1t, w2t,
                                             wsout, out, use_ws);
  if (use_ws) {
    gather_kernel<<<51200, 256, 0, stream>>>(wsout, fw, out);
  }
}

// Round 5
// 1423.285 us; speedup vs baseline: 1.0540x; 1.0540x over previous
//
#include <hip/hip_runtime.h>
#include <hip/hip_bf16.h>
#include <stdint.h>

typedef short bf16x8 __attribute__((ext_vector_type(8)));
typedef float f32x4 __attribute__((ext_vector_type(4)));
typedef unsigned short u16;
typedef unsigned int u32;

#define B_TOT 8192
#define NN 25

__device__ __forceinline__ u16 f2bf(float f) {
  u32 u = __float_as_uint(f);
  u32 r = (u + 0x7fffu + ((u >> 16) & 1u)) >> 16;   // RNE
  return (u16)r;
}
__device__ __forceinline__ float bf2f(u16 h) {
  return __uint_as_float(((u32)h) << 16);
}

// ---- group tables -------------------------------------------------------
__device__ __constant__ int d_IDXT[5][25] = {
  {0,1,2,3,4,5,6,7,8,9,10,11,12,13,14,15,16,17,18,19,20,21,22,23,24},
  {0,1,2,3,4,5,6,7,8, 0,0,0,0,0,0,0,0,0,0,0,0,0,0,0,0},
  {0,9,10,11,12,13,14, 0,0,0,0,0,0,0,0,0,0,0,0,0,0,0,0,0,0},
  {6,7,8,12,13,14, 0,0,0,0,0,0,0,0,0,0,0,0,0,0,0,0,0,0,0},
  {3,4,5,9,10,11, 0,0,0,0,0,0,0,0,0,0,0,0,0,0,0,0,0,0,0}
};
__device__ __constant__ int d_NG[5]    = {25, 9, 7, 6, 6};
__device__ __constant__ int d_BW[5]    = {1, 3, 4, 5, 5};       // batches per 32-row window
__device__ __constant__ int d_PREFN[5] = {0, 25, 34, 41, 47};   // prefix of n_g
// gather contributor tables: per output node v, list of (group, pos-in-group)
__device__ __constant__ int d_GCNT[25] = {3,2,2,3,3,3,3,3,3,3,3,3,3,3,3,1,1,1,1,1,1,1,1,1,1};
__device__ __constant__ signed char d_GG[25][3] = {
  {0,1,2},{0,1,0},{0,1,0},{0,1,4},{0,1,4},{0,1,4},{0,1,3},{0,1,3},{0,1,3},
  {0,2,4},{0,2,4},{0,2,4},{0,2,3},{0,2,3},{0,2,3},
  {0,0,0},{0,0,0},{0,0,0},{0,0,0},{0,0,0},{0,0,0},{0,0,0},{0,0,0},{0,0,0},{0,0,0}};
__device__ __constant__ signed char d_GP[25][3] = {
  {0,0,0},{1,1,0},{2,2,0},{3,3,0},{4,4,1},{5,5,2},{6,6,0},{7,7,1},{8,8,2},
  {9,1,3},{10,2,4},{11,3,5},{12,4,3},{13,5,4},{14,6,5},
  {15,0,0},{16,0,0},{17,0,0},{18,0,0},{19,0,0},{20,0,0},{21,0,0},{22,0,0},{23,0,0},{24,0,0}};

// ---- prep: W1 [5][256][512] -> w1t bf16 [5][512][256];  W2 [5][512][256] -> w2t bf16 [5][256][512]
__global__ __launch_bounds__(256) void prep_kernel(const float* __restrict__ W1,
                                                   const float* __restrict__ W2,
                                                   u16* __restrict__ w1t,
                                                   u16* __restrict__ w2t) {
  __shared__ float tile[32][33];
  int bid = blockIdx.x, t = threadIdx.x;
  const float* src; u16* dst; int R, C, tr, tc;
  if (bid < 640) {
    int g = bid >> 7, tI = bid & 127;
    R = 256; C = 512; tr = tI >> 4; tc = tI & 15;
    src = W1 + (size_t)g * 131072; dst = w1t + (size_t)g * 131072;
  } else {
    int b2 = bid - 640; int g = b2 >> 7, tI = b2 & 127;
    R = 512; C = 256; tr = tI >> 3; tc = tI & 7;
    src = W2 + (size_t)g * 131072; dst = w2t + (size_t)g * 131072;
  }
  for (int e = t; e < 1024; e += 256) {
    int r = e >> 5, c = e & 31;
    tile[r][c] = src[(size_t)(tr * 32 + r) * C + tc * 32 + c];
  }
  __syncthreads();
  for (int e = t; e < 1024; e += 256) {
    int c = e >> 5, r = e & 31;
    dst[(size_t)(tc * 32 + c) * R + tr * 32 + r] = f2bf(tile[r][c]);
  }
}

// ---- main per-group fused kernel ---------------------------------------
// grid: 4063 blocks; block b -> (group, tile). M = 128 rows (4 windows of 32),
// each window packs bw batches of n_g rows. 512 threads = 8 waves (2x4 wave grid).
// Weights are consumed as register B-fragments straight from global (L2-resident);
// only 2 barriers per feature chunk (sT-ready, hs-ready).
struct __align__(16) SMem {
  u16 xs[120 * 256];   // staged x (bf16, swizzled (r&7)<<4), rows = b_local*ng + i
  u16 bd[128 * 32];    // block-diag norm_adj (swizzled (row&3)<<4)
  u16 u[256 * 128];    // chunk: sT [f<128][mrow] | hs +32KB [mrow][f]; final: s2T [256 f][mrow]
  float b1s[512];
  float b2s[256];
  float dinv[500];     // [b_local*25 + i]
  u16 rowLUT[128];     // valid<<15 | b_local<<5 | i
};
static_assert(sizeof(SMem) <= 160 * 1024, "LDS overflow");

__global__ __launch_bounds__(512) void gcn_group_kernel(
    const float* __restrict__ x, const float* __restrict__ adj,
    const float* __restrict__ b1, const float* __restrict__ b2,
    const float* __restrict__ fw,
    const u16* __restrict__ w1t, const u16* __restrict__ w2t,
    u16* __restrict__ wsout, float* __restrict__ out, int use_ws) {
  __shared__ SMem sm;
  int bid = blockIdx.x;
  int g, tile;
  if (bid < 2048)      { g = 0; tile = bid; }
  else if (bid < 2731) { g = 1; tile = bid - 2048; }
  else if (bid < 3243) { g = 2; tile = bid - 2731; }
  else if (bid < 3653) { g = 3; tile = bid - 3243; }
  else                 { g = 4; tile = bid - 3653; }
  const int ng = d_NG[g], bw = d_BW[g];
  const int tb = bw * 4;               // batches per block
  const int tb0 = tile * tb;
  const int tid = threadIdx.x;
  const int lane = tid & 63, wid = tid >> 6, wm = wid >> 2, wn = wid & 3;

  // rowLUT: Mrow -> (valid, b_local, i)
  if (tid < 128) {
    int w = tid >> 5, off = tid & 31;
    int j = off / ng, i = off - j * ng;
    int valid = (j < bw) ? 1 : 0;
    int bl = w * bw + j;
    sm.rowLUT[tid] = (u16)((valid << 15) | ((bl & 31) << 5) | i);
  }
  sm.b1s[tid] = b1[g * 512 + tid];
  if (tid < 256) sm.b2s[tid] = b2[g * 256 + tid];

  // stage x -> bf16 LDS (swizzled); zero-fill batches >= B_TOT
  const int nrows = tb * ng;
  for (int cid = tid; cid < nrows * 64; cid += 512) {
    int r = cid >> 6, c4 = cid & 63;
    int bl = r / ng, i = r - bl * ng;
    int b = tb0 + bl;
    float4 v = make_float4(0.f, 0.f, 0.f, 0.f);
    if (b < B_TOT) {
      const float* p = x + ((size_t)b * NN + d_IDXT[g][i]) * 256 + c4 * 4;
      v = *(const float4*)p;
    }
    u32 p0 = (u32)f2bf(v.x) | ((u32)f2bf(v.y) << 16);
    u32 p1 = (u32)f2bf(v.z) | ((u32)f2bf(v.w) << 16);
    u32 off = (u32)r * 512u + (((u32)c4 * 8u) ^ (((u32)r & 7u) << 4));
    *(uint2*)((char*)sm.xs + off) = make_uint2(p0, p1);
  }

  // degrees -> dinv
  if (tid < nrows) {
    int bl = tid / ng, i = tid - bl * ng;
    int b = tb0 + bl;
    float s = 1.0f;  // +I diagonal
    if (b < B_TOT) {
      const float* ar = adj + ((size_t)b * NN + d_IDXT[g][i]) * NN;
      for (int j2 = 0; j2 < ng; ++j2) s += ar[d_IDXT[g][j2]];
    }
    sm.dinv[bl * 25 + i] = (s > 0.f) ? rsqrtf(s) : 0.f;
  }
  __syncthreads();

  // per-lane A-row bases for GEMM1 (xs row per Mfrag), invalid rows clamped to row 0
  u32 arow[4], aswz[4];
#pragma unroll
  for (int m = 0; m < 4; ++m) {
    int r = wm * 64 + m * 16 + (lane & 15);
    u16 lut = sm.rowLUT[r];
    int rxs = 0;
    if (lut & 0x8000) rxs = ((lut >> 5) & 31) * ng + (lut & 31);
    arow[m] = (u32)rxs * 512u;
    aswz[m] = ((u32)rxs & 7u) << 4;
  }

  // build BD (block-diagonal normalized adjacency), bf16, swizzled (row&3)<<4
  for (int e = tid; e < 4096; e += 512) {
    int r = e >> 5, c = e & 31;
    u16 lr = sm.rowLUT[r];
    u16 lc = sm.rowLUT[(r & ~31) | c];
    float val = 0.f;
    int blr = (lr >> 5) & 31, ir = lr & 31;
    int blc = (lc >> 5) & 31, ic = lc & 31;
    int b = tb0 + blr;
    if ((lr >> 15) && (lc >> 15) && blr == blc && b < B_TOT) {
      float a = adj[((size_t)b * NN + d_IDXT[g][ir]) * NN + d_IDXT[g][ic]] +
                (ir == ic ? 1.f : 0.f);
      val = sm.dinv[blr * 25 + ir] * a * sm.dinv[blr * 25 + ic];
    }
    u32 off = (u32)r * 64u + (((u32)c * 2u) ^ (((u32)r & 3u) << 4));
    *(u16*)((char*)sm.bd + off) = f2bf(val);
  }

  float wg = 0.2f;
  if (!use_ws) {  // softmax weight needed only for atomic path
    float a0 = fw[0], a1 = fw[1], a2 = fw[2], a3 = fw[3], a4 = fw[4];
    float mx = fmaxf(fmaxf(fmaxf(a0, a1), fmaxf(a2, a3)), a4);
    float e0 = __expf(a0 - mx), e1 = __expf(a1 - mx), e2 = __expf(a2 - mx),
          e3 = __expf(a3 - mx), e4 = __expf(a4 - mx);
    float es[5] = {e0, e1, e2, e3, e4};
    wg = es[g] / (e0 + e1 + e2 + e3 + e4);
  }

  f32x4 zero4 = {0.f, 0.f, 0.f, 0.f};
  f32x4 accO[4][2][2];
#pragma unroll
  for (int m = 0; m < 4; ++m)
#pragma unroll
    for (int a = 0; a < 2; ++a)
#pragma unroll
      for (int bq = 0; bq < 2; ++bq) accO[m][a][bq] = zero4;

  __syncthreads();   // xs/bd/dinv/LUT ready

  // ---- 4 chunks of 128 hidden features ----
#pragma unroll 1
  for (int c = 0; c < 4; ++c) {
    f32x4 accS[4][2];
#pragma unroll
    for (int m = 0; m < 4; ++m) { accS[m][0] = zero4; accS[m][1] = zero4; }

    // GEMM1: S_c = X (M x 256) @ W1[:, c*128 : +128]; weights from global (no barriers)
#pragma unroll
    for (int kt = 0; kt < 4; ++kt) {
      bf16x8 bfr[2][2];   // [ks][nf]
#pragma unroll
      for (int ks = 0; ks < 2; ++ks)
#pragma unroll
        for (int nf = 0; nf < 2; ++nf) {
          int n = c * 128 + (wn * 2 + nf) * 16 + (lane & 15);
          int k = kt * 64 + ks * 32 + ((lane >> 4) << 3);
          bfr[ks][nf] = *(const bf16x8*)(w1t + ((size_t)(g * 512 + n) * 256 + k));
        }
#pragma unroll
      for (int ks = 0; ks < 2; ++ks) {
        u32 colb = (u32)(kt * 128 + ks * 64) + (((u32)lane >> 4) << 4);
        bf16x8 afr[4];
#pragma unroll
        for (int m = 0; m < 4; ++m)
          afr[m] = *(const bf16x8*)((const char*)sm.xs + arow[m] + (colb ^ aswz[m]));
#pragma unroll
        for (int nf = 0; nf < 2; ++nf)
#pragma unroll
          for (int m = 0; m < 4; ++m)
            accS[m][nf] = __builtin_amdgcn_mfma_f32_16x16x32_bf16(afr[m], bfr[ks][nf], accS[m][nf], 0, 0, 0);
      }
    }

    // write S^T (bf16, swizzled): sT[f][mrow]; reg axis walks mrow -> packed uint2
    // (safe: all waves passed prior chunk's hs-ready barrier => prior mix1 sT reads done)
#pragma unroll
    for (int m = 0; m < 4; ++m) {
      int mrow0 = wm * 64 + m * 16 + ((lane >> 4) << 2);
#pragma unroll
      for (int nf = 0; nf < 2; ++nf) {
        int f = (wn * 2 + nf) * 16 + (lane & 15);
        u32 p0 = (u32)f2bf(accS[m][nf][0]) | ((u32)f2bf(accS[m][nf][1]) << 16);
        u32 p1 = (u32)f2bf(accS[m][nf][2]) | ((u32)f2bf(accS[m][nf][3]) << 16);
        u32 off = (u32)f * 256u + (((u32)mrow0 * 2u) ^ (((u32)f & 7u) << 4));
        *(uint2*)((char*)sm.u + off) = make_uint2(p0, p1);
      }
    }
    __syncthreads();   // barrier #1: sT ready (also: all waves done with prev-chunk GEMM2)

    // mix1 (operand-swapped): D[f][mrow] = sum_j sT[f][win*32+j] * BD[mrow][j]
    // reg axis walks f -> packed uint2 write of H[mrow][f]
#pragma unroll
    for (int m = 0; m < 4; ++m) {
      int mb = wm * 4 + m, win = mb >> 1;
      int mrow = mb * 16 + (lane & 15);
      u32 boff = (u32)mrow * 64u + (((((u32)lane >> 4) << 4)) ^ (((u32)mrow & 3u) << 4));
      bf16x8 bfr = *(const bf16x8*)((const char*)sm.bd + boff);
#pragma unroll
      for (int a = 0; a < 2; ++a) {
        int f = (wn * 2 + a) * 16 + (lane & 15);
        u32 aoff = (u32)f * 256u +
                   (((u32)(win * 64) + (((u32)lane >> 4) << 4)) ^ (((u32)f & 7u) << 4));
        bf16x8 afr = *(const bf16x8*)((const char*)sm.u + aoff);
        f32x4 d = __builtin_amdgcn_mfma_f32_16x16x32_bf16(afr, bfr, zero4, 0, 0, 0);
        int f0 = (wn * 2 + a) * 16 + ((lane >> 4) << 2);
        float4 bb = *(const float4*)&sm.b1s[c * 128 + f0];
        float h0 = d[0] + bb.x; h0 = h0 > 0.f ? h0 : 0.f;
        float h1 = d[1] + bb.y; h1 = h1 > 0.f ? h1 : 0.f;
        float h2 = d[2] + bb.z; h2 = h2 > 0.f ? h2 : 0.f;
        float h3 = d[3] + bb.w; h3 = h3 > 0.f ? h3 : 0.f;
        u32 p0 = (u32)f2bf(h0) | ((u32)f2bf(h1) << 16);
        u32 p1 = (u32)f2bf(h2) | ((u32)f2bf(h3) << 16);
        u32 hoff = 32768u + (u32)mrow * 256u + (((u32)f0 * 2u) ^ (((u32)mrow & 7u) << 4));
        *(uint2*)((char*)sm.u + hoff) = make_uint2(p0, p1);
      }
    }
    __syncthreads();   // barrier #2: hs ready

    // GEMM2 partial: accO += H (M x 128) @ W2[c*128 : +128, :]; weights from global
#pragma unroll
    for (int nh = 0; nh < 2; ++nh)
#pragma unroll
      for (int kt2 = 0; kt2 < 2; ++kt2) {
        bf16x8 bfr2[2][2];   // [ks][nf]
#pragma unroll
        for (int ks = 0; ks < 2; ++ks)
#pragma unroll
          for (int nf = 0; nf < 2; ++nf) {
            int n = nh * 128 + (wn * 2 + nf) * 16 + (lane & 15);
            int k = c * 128 + kt2 * 64 + ks * 32 + ((lane >> 4) << 3);
            bfr2[ks][nf] = *(const bf16x8*)(w2t + ((size_t)(g * 256 + n) * 512 + k));
          }
#pragma unroll
        for (int ks = 0; ks < 2; ++ks) {
          bf16x8 afr[4];
#pragma unroll
          for (int m = 0; m < 4; ++m) {
            int mrow = wm * 64 + m * 16 + (lane & 15);
            u32 aoff = 32768u + (u32)mrow * 256u +
                       (((u32)(kt2 * 128 + ks * 64) + (((u32)lane >> 4) << 4)) ^
                        (((u32)mrow & 7u) << 4));
            afr[m] = *(const bf16x8*)((const char*)sm.u + aoff);
          }
#pragma unroll
          for (int nf = 0; nf < 2; ++nf)
#pragma unroll
            for (int m = 0; m < 4; ++m)
              accO[m][nh][nf] =
                  __builtin_amdgcn_mfma_f32_16x16x32_bf16(afr[m], bfr2[ks][nf], accO[m][nh][nf], 0, 0, 0);
        }
      }
    // no barrier: next chunk's GEMM1 touches only xs/regs; sT overwrite is fenced by barrier #1
  }  // chunks

  __syncthreads();   // all GEMM2(3) hs reads done before s2T overwrites u

  // write S2^T [256 f][128 mrow] (bf16, swizzled) over full u buffer
#pragma unroll
  for (int m = 0; m < 4; ++m) {
    int mrow0 = wm * 64 + m * 16 + ((lane >> 4) << 2);
#pragma unroll
    for (int nh = 0; nh < 2; ++nh)
#pragma unroll
      for (int nf = 0; nf < 2; ++nf) {
        int f = nh * 128 + (wn * 2 + nf) * 16 + (lane & 15);
        u32 p0 = (u32)f2bf(accO[m][nh][nf][0]) | ((u32)f2bf(accO[m][nh][nf][1]) << 16);
        u32 p1 = (u32)f2bf(accO[m][nh][nf][2]) | ((u32)f2bf(accO[m][nh][nf][3]) << 16);
        u32 off = (u32)f * 256u + (((u32)mrow0 * 2u) ^ (((u32)f & 7u) << 4));
        *(uint2*)((char*)sm.u + off) = make_uint2(p0, p1);
      }
  }
  __syncthreads();

  // mix2 (operand-swapped): D[f][mrow] = sum_j s2T[f][win*32+j] * BD[mrow][j]; emit packed
  u16* wbase = wsout + (size_t)d_PREFN[g] * B_TOT * 256;
#pragma unroll
  for (int m = 0; m < 4; ++m) {
    int mb = wm * 4 + m, win = mb >> 1;
    int mrow = mb * 16 + (lane & 15);
    u32 boff = (u32)mrow * 64u + (((((u32)lane >> 4) << 4)) ^ (((u32)mrow & 3u) << 4));
    bf16x8 bfr = *(const bf16x8*)((const char*)sm.bd + boff);
    u16 lut = sm.rowLUT[mrow];
    int bl = (lut >> 5) & 31, i = lut & 31;
    int b = tb0 + bl;
    bool ok = (lut & 0x8000) && (b < B_TOT);
#pragma unroll
    for (int q = 0; q < 4; ++q) {
      int fb = wn * 4 + q;
      int f = fb * 16 + (lane & 15);
      u32 aoff = (u32)f * 256u +
                 (((u32)(win * 64) + (((u32)lane >> 4) << 4)) ^ (((u32)f & 7u) << 4));
      bf16x8 afr = *(const bf16x8*)((const char*)sm.u + aoff);
      f32x4 d = __builtin_amdgcn_mfma_f32_16x16x32_bf16(afr, bfr, zero4, 0, 0, 0);
      int f0 = fb * 16 + ((lane >> 4) << 2);
      float4 bb = *(const float4*)&sm.b2s[f0];
      float v0 = d[0] + bb.x; v0 = v0 > 0.f ? v0 : 0.f;
      float v1 = d[1] + bb.y; v1 = v1 > 0.f ? v1 : 0.f;
      float v2 = d[2] + bb.z; v2 = v2 > 0.f ? v2 : 0.f;
      float v3 = d[3] + bb.w; v3 = v3 > 0.f ? v3 : 0.f;
      if (ok) {
        if (use_ws) {
          u32 p0 = (u32)f2bf(v0) | ((u32)f2bf(v1) << 16);
          u32 p1 = (u32)f2bf(v2) | ((u32)f2bf(v3) << 16);
          *(uint2*)(wbase + ((size_t)b * ng + i) * 256 + f0) = make_uint2(p0, p1);
        } else {
          float* dst = out + ((size_t)b * NN + d_IDXT[g][i]) * 256 + f0;
          __hip_atomic_fetch_add(dst + 0, wg * v0, __ATOMIC_RELAXED, __HIP_MEMORY_SCOPE_AGENT);
          __hip_atomic_fetch_add(dst + 1, wg * v1, __ATOMIC_RELAXED, __HIP_MEMORY_SCOPE_AGENT);
          __hip_atomic_fetch_add(dst + 2, wg * v2, __ATOMIC_RELAXED, __HIP_MEMORY_SCOPE_AGENT);
          __hip_atomic_fetch_add(dst + 3, wg * v3, __ATOMIC_RELAXED, __HIP_MEMORY_SCOPE_AGENT);
        }
      }
    }
  }
}

// ---- gather: out[b][v][f] = sum_g w_g * wsout_g[b][pos][f] --------------
__global__ __launch_bounds__(256) void gather_kernel(const u16* __restrict__ wsout,
                                                     const float* __restrict__ fw,
                                                     float* __restrict__ out) {
  int t = blockIdx.x * 256 + threadIdx.x;   // one quad of floats
  int b = t / 1600;                          // 25*256/4 per batch
  int rem = t - b * 1600;
  int v = rem >> 6;
  int f = (rem & 63) << 2;
  float a0 = fw[0], a1 = fw[1], a2 = fw[2], a3 = fw[3], a4 = fw[4];
  float mx = fmaxf(fmaxf(fmaxf(a0, a1), fmaxf(a2, a3)), a4);
  float e0 = __expf(a0 - mx), e1 = __expf(a1 - mx), e2 = __expf(a2 - mx),
        e3 = __expf(a3 - mx), e4 = __expf(a4 - mx);
  float inv = 1.f / (e0 + e1 + e2 + e3 + e4);
  float w[5] = {e0 * inv, e1 * inv, e2 * inv, e3 * inv, e4 * inv};
  float acc0 = 0.f, acc1 = 0.f, acc2 = 0.f, acc3 = 0.f;
  int cnt = d_GCNT[v];
  for (int k = 0; k < cnt; ++k) {
    int g = d_GG[v][k], pos = d_GP[v][k];
    const u16* p = wsout + (size_t)d_PREFN[g] * B_TOT * 256 +
                   ((size_t)b * d_NG[g] + pos) * 256 + f;
    ushort4 h = *(const ushort4*)p;
    float ww = w[g];
    acc0 += ww * bf2f(h.x);
    acc1 += ww * bf2f(h.y);
    acc2 += ww * bf2f(h.z);
    acc3 += ww * bf2f(h.w);
  }
  *(float4*)(out + (size_t)t * 4) = make_float4(acc0, acc1, acc2, acc3);
}

// ---- host launch --------------------------------------------------------
extern "C" void kernel_launch(void* const* d_in, const int* in_sizes, int n_in,
                              void* d_out, int out_size, void* d_ws, size_t ws_size,
                              hipStream_t stream) {
  const float* x   = (const float*)d_in[0];
  const float* adj = (const float*)d_in[1];
  const float* W1  = (const float*)d_in[2];
  const float* b1  = (const float*)d_in[3];
  const float* W2  = (const float*)d_in[4];
  const float* b2  = (const float*)d_in[5];
  const float* fw  = (const float*)d_in[6];
  float* out = (float*)d_out;
  char* ws = (char*)d_ws;

  u16* w1t   = (u16*)ws;                        // 5*512*256*2 = 1310720 B
  u16* w2t   = (u16*)(ws + 1310720);            // 1310720 B
  u16* wsout = (u16*)(ws + 2621440);            // 53*8192*256*2 = 222298112 B
  const size_t need = 2621440ull + 53ull * 8192ull * 256ull * 2ull;
  const int use_ws = (ws_size >= need) ? 1 : 0;

  prep_kernel<<<1280, 256, 0, stream>>>(W1, W2, w1t, w2t);
  if (!use_ws) {
    hipMemsetAsync(out, 0, (size_t)out_size * sizeof(float), stream);
  }
  gcn_group_kernel<<<4063, 512, 0, stream>>>(x, adj, b1, b2, fw, w1t, w2t,
                                             wsout, out, use_ws);
  if (use_ws) {
    gather_kernel<<<51200, 256, 0, stream>>>(wsout, fw, out);
  }
}